// Round 3
// baseline (2613.418 us; speedup 1.0000x reference)
//
#include <hip/hip_runtime.h>
#include <hip/hip_bf16.h>
#include <math.h>

typedef __hip_bfloat16 bf16;

#define FEATN   256
#define HIDN    256
#define NHEADS  4
#define DHEAD   64
#define NTOK    2048
#define ROWS    8192        // B*N tokens per stream (x0 or x1)
#define TOKTOT  16384
#define SQS     0.35355339059327373f   // SCALE**0.5 = (DH^-0.5)^0.5

// ---------------------------------------------------------------------------
// Generic tiled GEMM: C[M,N] = A[M,K] @ B[N,K]^T (+epilogue), 64x64 tile,
// 256 threads, 4x4 per thread. All fp32. MODE selects sources+epilogue.
// MODE 0: proj = [x0;x1] @ [Wqk;Wv]^T, +bias, qk-half scaled. K=256,N=512
// MODE 1: p = m @ Wp^T + bp.                                 K=256,N=256
// MODE 2: h = [x|p] @ W1^T + b1  (concat fused into A load). K=512,N=512
// MODE 3: out = h_act @ W2^T + b2 + x  (fp32 out).           K=512,N=256
// ---------------------------------------------------------------------------
template<int MODE>
__global__ __launch_bounds__(256)
void gemm_k(const float* __restrict__ x0, const float* __restrict__ x1,
            const float* __restrict__ Wmain, const float* __restrict__ Waux,
            const float* __restrict__ bias0, const float* __restrict__ bias1,
            const float* __restrict__ Af,
            float* __restrict__ Cf)
{
    constexpr int K = (MODE == 0 || MODE == 1) ? 256 : 512;

    const int bx = blockIdx.x;          // N / 64
    const int by = blockIdx.y;          // M / 64
    const int tid = threadIdx.x;
    const int tx = tid & 15, ty = tid >> 4;
    const int row0 = by * 64, col0 = bx * 64;

    __shared__ float As[16][65];  // +1 pad: conflict-free transposed writes
    __shared__ float Bs[16][65];

    float acc[4][4] = {};

    for (int k0 = 0; k0 < K; k0 += 16) {
        // ---- stage A tile (64 rows x 16 k) ----
        #pragma unroll
        for (int l = 0; l < 4; ++l) {
            int e  = tid + l * 256;
            int mi = e >> 4, ki = e & 15;
            int row = row0 + mi, kk = k0 + ki;
            float v;
            if (MODE == 0) {
                const float* p = (row < ROWS) ? (x0 + (size_t)row * FEATN)
                                              : (x1 + (size_t)(row - ROWS) * FEATN);
                v = p[kk];
            } else if (MODE == 2) {
                if (kk < 256) {
                    const float* p = (row < ROWS) ? (x0 + (size_t)row * FEATN)
                                                  : (x1 + (size_t)(row - ROWS) * FEATN);
                    v = p[kk];
                } else {
                    v = Af[(size_t)row * 256 + (kk - 256)];
                }
            } else {
                v = Af[(size_t)row * K + kk];
            }
            As[ki][mi] = v;
        }
        // ---- stage B tile (64 cols x 16 k) ----
        #pragma unroll
        for (int l = 0; l < 4; ++l) {
            int e  = tid + l * 256;
            int ni = e >> 4, ki = e & 15;
            int col = col0 + ni, kk = k0 + ki;
            float v;
            if (MODE == 0) {
                v = (col < 256) ? Wmain[(size_t)col * 256 + kk]
                                : Waux[(size_t)(col - 256) * 256 + kk];
            } else {
                v = Wmain[(size_t)col * K + kk];
            }
            Bs[ki][ni] = v;
        }
        __syncthreads();

        #pragma unroll
        for (int k = 0; k < 16; ++k) {
            float a[4], b[4];
            #pragma unroll
            for (int i = 0; i < 4; ++i) a[i] = As[k][ty * 4 + i];
            #pragma unroll
            for (int j = 0; j < 4; ++j) b[j] = Bs[k][tx * 4 + j];
            #pragma unroll
            for (int i = 0; i < 4; ++i)
                #pragma unroll
                for (int j = 0; j < 4; ++j)
                    acc[i][j] += a[i] * b[j];
        }
        __syncthreads();
    }

    // ---- epilogue ----
    #pragma unroll
    for (int i = 0; i < 4; ++i) {
        int row = row0 + ty * 4 + i;
        #pragma unroll
        for (int j = 0; j < 4; ++j) {
            int col = col0 + tx * 4 + j;
            float v = acc[i][j];
            if (MODE == 0) {
                // bias BEFORE scale, per reference: (xW + b) * sqrt(SCALE)
                if (col < 256) v = (v + bias0[col]) * SQS;
                else           v =  v + bias1[col - 256];
                Cf[(size_t)row * 512 + col] = v;
            } else if (MODE == 1) {
                Cf[(size_t)row * 256 + col] = v + bias0[col];
            } else if (MODE == 2) {
                Cf[(size_t)row * 512 + col] = v + bias0[col];
            } else {
                const float* xr = (row < ROWS) ? (x0 + (size_t)row * FEATN)
                                               : (x1 + (size_t)(row - ROWS) * FEATN);
                Cf[(size_t)row * 256 + col] = v + bias0[col] + xr[col];
            }
        }
    }
}

// ---------------------------------------------------------------------------
// Flash cross-attention. proj layout: [tok,512] = [qk(scaled) | v], fp32.
// dir 0: Q from x0 tokens, K/V from x1 tokens -> m0. dir 1: swapped -> m1.
// One thread per query row; online softmax over 16-key LDS tiles.
// Output mbuf[tok, 256] in merged head layout (hid = h*64+d).
// ---------------------------------------------------------------------------
__global__ __launch_bounds__(256)
void attn_k(const float* __restrict__ proj, float* __restrict__ mbuf)
{
    const int rb  = blockIdx.x;    // 0..7 (256-row blocks)
    const int bh  = blockIdx.y;    // 0..15
    const int dir = blockIdx.z;    // 0..1
    const int b = bh >> 2, h = bh & 3;
    const int tid = threadIdx.x;

    const int qbase = (dir == 0 ? 0 : ROWS) + b * NTOK;
    const int kbase = (dir == 0 ? ROWS : 0) + b * NTOK;

    const int qrow = rb * 256 + tid;
    const float* qptr = proj + (size_t)(qbase + qrow) * 512 + h * DHEAD;

    float q[64];
    #pragma unroll
    for (int i = 0; i < 16; ++i) {
        float4 v = ((const float4*)qptr)[i];
        q[i*4+0] = v.x; q[i*4+1] = v.y; q[i*4+2] = v.z; q[i*4+3] = v.w;
    }

    float acc[64] = {};
    float mrun = -INFINITY, lrun = 0.f;

    __shared__ float Ks[16][64];
    __shared__ float Vs[16][64];

    for (int j0 = 0; j0 < NTOK; j0 += 16) {
        // one float4 per thread per array: tid -> (row j = tid>>4, d4 = tid&15)
        {
            int j  = tid >> 4, d4 = tid & 15;
            const float* krow = proj + (size_t)(kbase + j0 + j) * 512 + h * DHEAD;
            ((float4*)&Ks[j][d4 * 4])[0] = *(const float4*)(krow + d4 * 4);
            ((float4*)&Vs[j][d4 * 4])[0] = *(const float4*)(krow + 256 + d4 * 4);
        }
        __syncthreads();

        float s[16];
        #pragma unroll
        for (int j = 0; j < 16; ++j) {
            float d0 = 0.f;
            #pragma unroll
            for (int d = 0; d < 64; ++d) d0 += q[d] * Ks[j][d];
            s[j] = d0;
        }
        float tmax = s[0];
        #pragma unroll
        for (int j = 1; j < 16; ++j) tmax = fmaxf(tmax, s[j]);
        float nm = fmaxf(mrun, tmax);
        float alpha = __expf(mrun - nm);   // first tile: exp(-inf)=0
        lrun *= alpha;
        #pragma unroll
        for (int d = 0; d < 64; ++d) acc[d] *= alpha;
        #pragma unroll
        for (int j = 0; j < 16; ++j) {
            float p = __expf(s[j] - nm);
            lrun += p;
            #pragma unroll
            for (int d = 0; d < 64; ++d) acc[d] += p * Vs[j][d];
        }
        mrun = nm;
        __syncthreads();
    }

    float inv = 1.f / lrun;
    float* op = mbuf + (size_t)(qbase + qrow) * 256 + h * DHEAD;
    #pragma unroll
    for (int i = 0; i < 16; ++i) {
        float4 v = make_float4(acc[i*4+0]*inv, acc[i*4+1]*inv,
                               acc[i*4+2]*inv, acc[i*4+3]*inv);
        ((float4*)op)[i] = v;
    }
}

// ---------------------------------------------------------------------------
// In-place LayerNorm(512, eps=1e-5) + exact GELU. One wave per row.
// ---------------------------------------------------------------------------
__global__ __launch_bounds__(256)
void ln_gelu_k(float* __restrict__ h, const float* __restrict__ gamma,
               const float* __restrict__ beta)
{
    const int wave = threadIdx.x >> 6;
    const int lane = threadIdx.x & 63;
    const int row  = blockIdx.x * 4 + wave;
    float* hp = h + (size_t)row * 512;

    float v[8];
    float s1 = 0.f, s2 = 0.f;
    #pragma unroll
    for (int i = 0; i < 8; ++i) {
        v[i] = hp[lane + i * 64];
        s1 += v[i]; s2 += v[i] * v[i];
    }
    #pragma unroll
    for (int off = 32; off; off >>= 1) {
        s1 += __shfl_xor(s1, off);
        s2 += __shfl_xor(s2, off);
    }
    float mean = s1 * (1.f / 512.f);
    float var  = s2 * (1.f / 512.f) - mean * mean;
    float rstd = rsqrtf(var + 1e-5f);
    #pragma unroll
    for (int i = 0; i < 8; ++i) {
        int o = lane + i * 64;
        float y = (v[i] - mean) * rstd * gamma[o] + beta[o];
        float g = 0.5f * y * (1.f + erff(y * 0.70710678118654752f));
        hp[o] = g;
    }
}

// ---------------------------------------------------------------------------
extern "C" void kernel_launch(void* const* d_in, const int* in_sizes, int n_in,
                              void* d_out, int out_size, void* d_ws, size_t ws_size,
                              hipStream_t stream)
{
    const float* x0    = (const float*)d_in[0];
    const float* x1    = (const float*)d_in[1];
    const float* Wqk   = (const float*)d_in[2];
    const float* bqk   = (const float*)d_in[3];
    const float* Wv    = (const float*)d_in[4];
    const float* bv    = (const float*)d_in[5];
    const float* Wp    = (const float*)d_in[6];
    const float* bp    = (const float*)d_in[7];
    const float* W1    = (const float*)d_in[8];
    const float* b1    = (const float*)d_in[9];
    const float* gamma = (const float*)d_in[10];
    const float* beta  = (const float*)d_in[11];
    const float* W2    = (const float*)d_in[12];
    const float* b2    = (const float*)d_in[13];
    float* out = (float*)d_out;   // reference output dtype is float32

    char* ws = (char*)d_ws;
    // fp32 workspace, peak 48 MB with reuse:
    //   proj [16384,512] @ [0,32M)   (dead after attn)
    //   m    [16384,256] @ [32,48M)  (dead after gemm<1>)
    //   p    [16384,256] @ [0,16M)   (overlays dead proj)
    //   h    [16384,512] @ [16,48M)  (overlays dead proj tail + m)
    float* proj = (float*)ws;
    float* mbuf = (float*)(ws + (size_t)32 * 1024 * 1024);
    float* pbuf = (float*)ws;
    float* hbuf = (float*)(ws + (size_t)16 * 1024 * 1024);

    // 1. fused QK+V projection (both streams)
    gemm_k<0><<<dim3(8, 256), 256, 0, stream>>>(x0, x1, Wqk, Wv, bqk, bv,
                                                nullptr, proj);
    // 2. cross-attention, both directions
    attn_k<<<dim3(8, 16, 2), 256, 0, stream>>>(proj, mbuf);
    // 3. p = m @ Wp^T + bp
    gemm_k<1><<<dim3(4, 256), 256, 0, stream>>>(x0, x1, Wp, nullptr, bp, nullptr,
                                                mbuf, pbuf);
    // 4. h = [x|p] @ W1^T + b1   (concat fused into A load)
    gemm_k<2><<<dim3(8, 256), 256, 0, stream>>>(x0, x1, W1, nullptr, b1, nullptr,
                                                pbuf, hbuf);
    // 5. h = gelu(layernorm(h)) in place
    ln_gelu_k<<<4096, 256, 0, stream>>>(hbuf, gamma, beta);
    // 6. out = x + h @ W2^T + b2  (fp32)
    gemm_k<3><<<dim3(4, 256), 256, 0, stream>>>(x0, x1, W2, nullptr, b2, nullptr,
                                                hbuf, out);
}

// Round 4
// 366.351 us; speedup vs baseline: 7.1337x; 7.1337x over previous
//
#include <hip/hip_runtime.h>
#include <hip/hip_bf16.h>
#include <math.h>

typedef __hip_bfloat16 hbf;
typedef __attribute__((ext_vector_type(8))) short short8;   // 8 bf16 (4 VGPRs)
typedef __attribute__((ext_vector_type(4))) short short4v;  // 4 bf16
typedef __attribute__((ext_vector_type(4))) float f32x4;    // MFMA acc

#define ROWS 8192
#define SQS  0.35355339059327373f   // sqrt(DH^-0.5)

__device__ __forceinline__ short f2b(float f) {
    union { hbf h; short s; } u; u.h = __float2bfloat16(f); return u.s;
}
__device__ __forceinline__ float b2f(short s) {
    union { unsigned u; float f; } x;
    x.u = ((unsigned)(unsigned short)s) << 16; return x.f;
}

// ---------------------------------------------------------------------------
// MFMA GEMM: C[M,N] = A[M,K] @ W[N,K]^T (+epilogue). 128x128 block, 4 waves,
// each wave 64x64 (4x4 MFMA 16x16x32 tiles), BK=32. A/B staged fp32->bf16.
// MODE 0: proj = [x0;x1] @ [Wqk;Wv]^T, +bias, qk-half *SQS. K=256 -> bf16
// MODE 1: p = m(bf16) @ Wp^T + bp.                          K=256 -> bf16
// MODE 2: h = [x|p] @ W1^T + b1.                            K=512 -> bf16
// MODE 3: out = h(bf16) @ W2^T + b2 + x.                    K=512 -> fp32
// ---------------------------------------------------------------------------
template<int MODE>
__global__ __launch_bounds__(256)
void gemm2(const float* __restrict__ x0, const float* __restrict__ x1,
           const float* __restrict__ Wq, const float* __restrict__ Wvw,
           const float* __restrict__ bias0, const float* __restrict__ bias1,
           const short* __restrict__ Abf,
           short* __restrict__ Cb, float* __restrict__ Cf)
{
    constexpr int K = (MODE == 0 || MODE == 1) ? 256 : 512;

    const int col0 = blockIdx.x * 128;
    const int row0 = blockIdx.y * 128;
    const int tid  = threadIdx.x;
    const int lane = tid & 63, wave = tid >> 6;
    const int ln   = lane & 15, quad = lane >> 4;
    const int wm   = wave & 1,  wn   = wave >> 1;

    __shared__ short As[128 * 40];   // stride 40 bf16: 2-way bank alias (free)
    __shared__ short Bs[128 * 40];

    const float* Wsrc; int cw;
    if (MODE == 0) {
        if (col0 < 256) { Wsrc = Wq;  cw = col0; }
        else            { Wsrc = Wvw; cw = col0 - 256; }
    } else { Wsrc = Wq; cw = col0; }

    const int c4 = tid & 7;    // k-chunk of 4
    const int rg = tid >> 3;   // 0..31

    f32x4 acc[4][4];
    #pragma unroll
    for (int i = 0; i < 4; ++i)
        #pragma unroll
        for (int j = 0; j < 4; ++j) acc[i][j] = {0.f, 0.f, 0.f, 0.f};

    for (int k0 = 0; k0 < K; k0 += 32) {
        #pragma unroll
        for (int g = 0; g < 4; ++g) {
            int r = rg + g * 32;
            int row = row0 + r;
            int kk = k0 + c4 * 4;
            short4v s;
            if (MODE == 0 || (MODE == 2 && kk < 256)) {
                const float* p = (row < ROWS ? x0 + (size_t)row * 256
                                             : x1 + (size_t)(row - ROWS) * 256) + kk;
                float4 f = *(const float4*)p;
                s[0] = f2b(f.x); s[1] = f2b(f.y); s[2] = f2b(f.z); s[3] = f2b(f.w);
            } else if (MODE == 1) {
                s = *(const short4v*)(Abf + (size_t)row * 256 + kk);
            } else if (MODE == 2) {
                s = *(const short4v*)(Abf + (size_t)row * 256 + (kk - 256));
            } else {
                s = *(const short4v*)(Abf + (size_t)row * 512 + kk);
            }
            *(short4v*)&As[r * 40 + c4 * 4] = s;

            const float* wp = Wsrc + (size_t)(cw + r) * K + kk;
            float4 fw = *(const float4*)wp;
            short4v sw;
            sw[0] = f2b(fw.x); sw[1] = f2b(fw.y); sw[2] = f2b(fw.z); sw[3] = f2b(fw.w);
            *(short4v*)&Bs[r * 40 + c4 * 4] = sw;
        }
        __syncthreads();

        short8 a[4], b[4];
        #pragma unroll
        for (int mi = 0; mi < 4; ++mi)
            a[mi] = *(const short8*)&As[(wm * 64 + mi * 16 + ln) * 40 + quad * 8];
        #pragma unroll
        for (int nj = 0; nj < 4; ++nj)
            b[nj] = *(const short8*)&Bs[(wn * 64 + nj * 16 + ln) * 40 + quad * 8];
        #pragma unroll
        for (int mi = 0; mi < 4; ++mi)
            #pragma unroll
            for (int nj = 0; nj < 4; ++nj)
                acc[mi][nj] = __builtin_amdgcn_mfma_f32_16x16x32_bf16(
                                  a[mi], b[nj], acc[mi][nj], 0, 0, 0);
        __syncthreads();
    }

    #pragma unroll
    for (int mi = 0; mi < 4; ++mi)
        #pragma unroll
        for (int nj = 0; nj < 4; ++nj)
            #pragma unroll
            for (int r = 0; r < 4; ++r) {
                int row = row0 + wm * 64 + mi * 16 + quad * 4 + r;
                int col = col0 + wn * 64 + nj * 16 + ln;
                float v = acc[mi][nj][r];
                if (MODE == 0) {
                    v = (col < 256) ? (v + bias0[col]) * SQS : (v + bias1[col - 256]);
                    Cb[(size_t)row * 512 + col] = f2b(v);
                } else if (MODE == 1) {
                    Cb[(size_t)row * 256 + col] = f2b(v + bias0[col]);
                } else if (MODE == 2) {
                    Cb[(size_t)row * 512 + col] = f2b(v + bias0[col]);
                } else {
                    const float* xr = (row < ROWS ? x0 + (size_t)row * 256
                                                  : x1 + (size_t)(row - ROWS) * 256);
                    Cf[(size_t)row * 256 + col] = v + bias0[col] + xr[col];
                }
            }
}

// ---------------------------------------------------------------------------
// MFMA flash cross-attention. proj bf16 [tok,512] = [qk*SQS | v].
// Block: one (dir, b, h, 128-row Q tile). 4 waves, each 32 Q rows.
// KV tiles of 64. S via MFMA; online softmax on C-layout frags (row=quad*4+r,
// shuffle-xor 1,2,4,8 for row reductions); P -> bf16 -> LDS (C->A layout
// round-trip); O += P@V with V transposed in LDS. Out mbuf bf16 [tok,256].
// ---------------------------------------------------------------------------
__global__ __launch_bounds__(256)
void attn2(const short* __restrict__ proj, short* __restrict__ mbuf)
{
    const int qt  = blockIdx.x;            // 0..15
    const int b   = blockIdx.y >> 2, h = blockIdx.y & 3;
    const int dir = blockIdx.z;
    const int tid = threadIdx.x;
    const int lane = tid & 63, wave = tid >> 6;
    const int ln   = lane & 15, quad = lane >> 4;

    const int qbase = dir * ROWS + b * 2048;
    const int kbase = (1 - dir) * ROWS + b * 2048;

    __shared__ short Qs[128 * 72];
    __shared__ short Ks[64 * 72];
    __shared__ short Vt[64 * 72];   // V transposed: Vt[d][kv]
    __shared__ short Ps[128 * 72];

    {   // load Q tile (128 x 64)
        int d8 = tid & 7, r0 = tid >> 3;
        #pragma unroll
        for (int g = 0; g < 4; ++g) {
            int r = r0 + g * 32;
            short8 s = *(const short8*)(proj + (size_t)(qbase + qt * 128 + r) * 512
                                        + h * 64 + d8 * 8);
            *(short8*)&Qs[r * 72 + d8 * 8] = s;
        }
    }
    __syncthreads();

    short8 qf[2][2];
    #pragma unroll
    for (int mi = 0; mi < 2; ++mi)
        #pragma unroll
        for (int ks = 0; ks < 2; ++ks)
            qf[mi][ks] = *(const short8*)&Qs[(wave * 32 + mi * 16 + ln) * 72
                                             + ks * 32 + quad * 8];

    f32x4 O[2][4];
    float mrun[2][4], lrun[2][4];
    #pragma unroll
    for (int mi = 0; mi < 2; ++mi) {
        #pragma unroll
        for (int nj = 0; nj < 4; ++nj) O[mi][nj] = {0.f, 0.f, 0.f, 0.f};
        #pragma unroll
        for (int r = 0; r < 4; ++r) { mrun[mi][r] = -1e30f; lrun[mi][r] = 0.f; }
    }

    for (int j0 = 0; j0 < 2048; j0 += 64) {
        {   // stage K (64x64) and V transposed (64x64 -> Vt[d][kv])
            int d8 = tid & 7, r0 = tid >> 3;
            #pragma unroll
            for (int g = 0; g < 2; ++g) {
                int r = r0 + g * 32;
                short8 s = *(const short8*)(proj + (size_t)(kbase + j0 + r) * 512
                                            + h * 64 + d8 * 8);
                *(short8*)&Ks[r * 72 + d8 * 8] = s;
            }
            int d4 = tid & 15, jj = tid >> 4;
            #pragma unroll
            for (int g = 0; g < 4; ++g) {
                int r = jj + g * 16;
                short4v s = *(const short4v*)(proj + (size_t)(kbase + j0 + r) * 512
                                              + 256 + h * 64 + d4 * 4);
                #pragma unroll
                for (int i = 0; i < 4; ++i) Vt[(d4 * 4 + i) * 72 + r] = s[i];
            }
        }
        __syncthreads();

        // S = Q @ K^T   (2 mi x 4 nj tiles, 2 K-steps over dh=64)
        f32x4 S[2][4];
        #pragma unroll
        for (int mi = 0; mi < 2; ++mi)
            #pragma unroll
            for (int nj = 0; nj < 4; ++nj) S[mi][nj] = {0.f, 0.f, 0.f, 0.f};
        short8 kf[4][2];
        #pragma unroll
        for (int nj = 0; nj < 4; ++nj)
            #pragma unroll
            for (int ks = 0; ks < 2; ++ks)
                kf[nj][ks] = *(const short8*)&Ks[(nj * 16 + ln) * 72 + ks * 32 + quad * 8];
        #pragma unroll
        for (int mi = 0; mi < 2; ++mi)
            #pragma unroll
            for (int nj = 0; nj < 4; ++nj) {
                S[mi][nj] = __builtin_amdgcn_mfma_f32_16x16x32_bf16(
                                qf[mi][0], kf[nj][0], S[mi][nj], 0, 0, 0);
                S[mi][nj] = __builtin_amdgcn_mfma_f32_16x16x32_bf16(
                                qf[mi][1], kf[nj][1], S[mi][nj], 0, 0, 0);
            }

        // online softmax (row = quad*4 + r; cols across 16 lanes + 4 nj tiles)
        float aexp[2][4];
        #pragma unroll
        for (int mi = 0; mi < 2; ++mi)
            #pragma unroll
            for (int r = 0; r < 4; ++r) {
                float t = S[mi][0][r];
                #pragma unroll
                for (int nj = 1; nj < 4; ++nj) t = fmaxf(t, S[mi][nj][r]);
                t = fmaxf(t, __shfl_xor(t, 1));
                t = fmaxf(t, __shfl_xor(t, 2));
                t = fmaxf(t, __shfl_xor(t, 4));
                t = fmaxf(t, __shfl_xor(t, 8));
                float mn = fmaxf(mrun[mi][r], t);
                aexp[mi][r] = __expf(mrun[mi][r] - mn);
                mrun[mi][r] = mn;
            }
        float rs[2][4];
        #pragma unroll
        for (int mi = 0; mi < 2; ++mi)
            #pragma unroll
            for (int r = 0; r < 4; ++r) rs[mi][r] = 0.f;
        #pragma unroll
        for (int mi = 0; mi < 2; ++mi)
            #pragma unroll
            for (int nj = 0; nj < 4; ++nj)
                #pragma unroll
                for (int r = 0; r < 4; ++r) {
                    float p = __expf(S[mi][nj][r] - mrun[mi][r]);
                    rs[mi][r] += p;
                    Ps[(wave * 32 + mi * 16 + quad * 4 + r) * 72 + nj * 16 + ln] = f2b(p);
                }
        #pragma unroll
        for (int mi = 0; mi < 2; ++mi)
            #pragma unroll
            for (int r = 0; r < 4; ++r) {
                float t = rs[mi][r];
                t += __shfl_xor(t, 1);
                t += __shfl_xor(t, 2);
                t += __shfl_xor(t, 4);
                t += __shfl_xor(t, 8);
                lrun[mi][r] = lrun[mi][r] * aexp[mi][r] + t;
            }
        #pragma unroll
        for (int mi = 0; mi < 2; ++mi)
            #pragma unroll
            for (int nj = 0; nj < 4; ++nj)
                #pragma unroll
                for (int r = 0; r < 4; ++r) O[mi][nj][r] *= aexp[mi][r];
        __syncthreads();   // Ps write -> read

        // O += P @ V
        short8 pa[2][2], vb[4][2];
        #pragma unroll
        for (int mi = 0; mi < 2; ++mi)
            #pragma unroll
            for (int ks = 0; ks < 2; ++ks)
                pa[mi][ks] = *(const short8*)&Ps[(wave * 32 + mi * 16 + ln) * 72
                                                 + ks * 32 + quad * 8];
        #pragma unroll
        for (int nj = 0; nj < 4; ++nj)
            #pragma unroll
            for (int ks = 0; ks < 2; ++ks)
                vb[nj][ks] = *(const short8*)&Vt[(nj * 16 + ln) * 72 + ks * 32 + quad * 8];
        #pragma unroll
        for (int mi = 0; mi < 2; ++mi)
            #pragma unroll
            for (int nj = 0; nj < 4; ++nj) {
                O[mi][nj] = __builtin_amdgcn_mfma_f32_16x16x32_bf16(
                                pa[mi][0], vb[nj][0], O[mi][nj], 0, 0, 0);
                O[mi][nj] = __builtin_amdgcn_mfma_f32_16x16x32_bf16(
                                pa[mi][1], vb[nj][1], O[mi][nj], 0, 0, 0);
            }
        __syncthreads();   // Ks/Vt/Ps reads done before next stage
    }

    #pragma unroll
    for (int mi = 0; mi < 2; ++mi)
        #pragma unroll
        for (int r = 0; r < 4; ++r) {
            float linv = 1.f / lrun[mi][r];
            #pragma unroll
            for (int nj = 0; nj < 4; ++nj) {
                int row = qbase + qt * 128 + wave * 32 + mi * 16 + quad * 4 + r;
                mbuf[(size_t)row * 256 + h * 64 + nj * 16 + ln] =
                    f2b(O[mi][nj][r] * linv);
            }
        }
}

// ---------------------------------------------------------------------------
// In-place LayerNorm(512) + exact GELU on bf16 rows. One wave per row.
// ---------------------------------------------------------------------------
__global__ __launch_bounds__(256)
void ln_gelu2(short* __restrict__ h, const float* __restrict__ gamma,
              const float* __restrict__ beta)
{
    const int wave = threadIdx.x >> 6, lane = threadIdx.x & 63;
    const int row = blockIdx.x * 4 + wave;
    short* hp = h + (size_t)row * 512 + lane * 8;
    short8 sv = *(const short8*)hp;
    float v[8], s1 = 0.f, s2 = 0.f;
    #pragma unroll
    for (int i = 0; i < 8; ++i) { v[i] = b2f(sv[i]); s1 += v[i]; s2 += v[i] * v[i]; }
    #pragma unroll
    for (int off = 32; off; off >>= 1) {
        s1 += __shfl_xor(s1, off);
        s2 += __shfl_xor(s2, off);
    }
    float mean = s1 * (1.f / 512.f);
    float var  = s2 * (1.f / 512.f) - mean * mean;
    float rstd = rsqrtf(var + 1e-5f);
    #pragma unroll
    for (int i = 0; i < 8; ++i) {
        int o = lane * 8 + i;
        float y = (v[i] - mean) * rstd * gamma[o] + beta[o];
        float g = 0.5f * y * (1.f + erff(y * 0.70710678118654752f));
        sv[i] = f2b(g);
    }
    *(short8*)hp = sv;
}

// ---------------------------------------------------------------------------
extern "C" void kernel_launch(void* const* d_in, const int* in_sizes, int n_in,
                              void* d_out, int out_size, void* d_ws, size_t ws_size,
                              hipStream_t stream)
{
    const float* x0    = (const float*)d_in[0];
    const float* x1    = (const float*)d_in[1];
    const float* Wqk   = (const float*)d_in[2];
    const float* bqk   = (const float*)d_in[3];
    const float* Wv    = (const float*)d_in[4];
    const float* bv    = (const float*)d_in[5];
    const float* Wp    = (const float*)d_in[6];
    const float* bp    = (const float*)d_in[7];
    const float* W1    = (const float*)d_in[8];
    const float* b1    = (const float*)d_in[9];
    const float* gamma = (const float*)d_in[10];
    const float* beta  = (const float*)d_in[11];
    const float* W2    = (const float*)d_in[12];
    const float* b2    = (const float*)d_in[13];
    float* out = (float*)d_out;

    char* ws = (char*)d_ws;
    // bf16 workspace, 48 MB total, all disjoint:
    short* proj = (short*)ws;                                   // [16384,512] 16 MB
    short* mbuf = (short*)(ws + (size_t)16 * 1024 * 1024);      // [16384,256]  8 MB
    short* pbuf = (short*)(ws + (size_t)24 * 1024 * 1024);      // [16384,256]  8 MB
    short* hbuf = (short*)(ws + (size_t)32 * 1024 * 1024);      // [16384,512] 16 MB

    gemm2<0><<<dim3(4, 128), 256, 0, stream>>>(x0, x1, Wqk, Wv, bqk, bv,
                                               nullptr, proj, nullptr);
    attn2<<<dim3(16, 16, 2), 256, 0, stream>>>(proj, mbuf);
    gemm2<1><<<dim3(2, 128), 256, 0, stream>>>(x0, x1, Wp, nullptr, bp, nullptr,
                                               mbuf, pbuf, nullptr);
    gemm2<2><<<dim3(4, 128), 256, 0, stream>>>(x0, x1, W1, nullptr, b1, nullptr,
                                               pbuf, hbuf, nullptr);
    ln_gelu2<<<4096, 256, 0, stream>>>(hbuf, gamma, beta);
    gemm2<3><<<dim3(2, 128), 256, 0, stream>>>(x0, x1, W2, nullptr, b2, nullptr,
                                               hbuf, nullptr, out);
}

// Round 5
// 322.844 us; speedup vs baseline: 8.0950x; 1.1348x over previous
//
#include <hip/hip_runtime.h>
#include <hip/hip_bf16.h>
#include <math.h>

typedef __hip_bfloat16 hbf;
typedef __attribute__((ext_vector_type(8))) short short8;   // 8 bf16
typedef __attribute__((ext_vector_type(4))) short short4v;  // 4 bf16
typedef __attribute__((ext_vector_type(4))) float f32x4;

#define ROWS 8192
#define SQS  0.35355339059327373f   // sqrt(DH^-0.5)
#define L2E  1.4426950408889634f

__device__ __forceinline__ short f2b(float f) {
    union { hbf h; short s; } u; u.h = __float2bfloat16(f); return u.s;
}
__device__ __forceinline__ float b2f(short s) {
    union { unsigned u; float f; } x;
    x.u = ((unsigned)(unsigned short)s) << 16; return x.f;
}

// ---------------------------------------------------------------------------
// fp32 -> bf16 bulk convert. blockIdx.y selects source; one float4 per thread.
// ---------------------------------------------------------------------------
__global__ __launch_bounds__(256)
void cvt_all(const float* __restrict__ x0, const float* __restrict__ x1,
             const float* __restrict__ Wqk, const float* __restrict__ Wv,
             const float* __restrict__ Wp, const float* __restrict__ W1,
             const float* __restrict__ W2,
             short* __restrict__ xbf, short* __restrict__ wq,
             short* __restrict__ wv, short* __restrict__ wp,
             short* __restrict__ w1, short* __restrict__ w2)
{
    const int y = blockIdx.y;
    const float* src; short* dst; int n;  // n in float4 units
    switch (y) {
    case 0: src = x0;  dst = xbf;               n = 524288; break;
    case 1: src = x1;  dst = xbf + 8192 * 256;  n = 524288; break;
    case 2: src = Wqk; dst = wq;                n = 16384;  break;
    case 3: src = Wv;  dst = wv;                n = 16384;  break;
    case 4: src = Wp;  dst = wp;                n = 16384;  break;
    case 5: src = W1;  dst = w1;                n = 65536;  break;
    default: src = W2; dst = w2;                n = 32768;  break;
    }
    int i = blockIdx.x * 256 + threadIdx.x;
    if (i >= n) return;
    float4 f = ((const float4*)src)[i];
    short4v s; s[0] = f2b(f.x); s[1] = f2b(f.y); s[2] = f2b(f.z); s[3] = f2b(f.w);
    *(short4v*)(dst + (size_t)i * 4) = s;
}

// ---------------------------------------------------------------------------
// MFMA GEMM, all-bf16 operands: C[M,N] = A @ W^T (+epilogue).
// 128x128 block, 4 waves x (4x4) 16x16x32 tiles, BK=32, LDS stride 40.
// MODE 0: proj = xbf @ [wq;wv]^T, +bias fp32, qk-half *SQS -> bf16
// MODE 1: p = mbuf @ wp^T + bp -> bf16
// MODE 2: h = [xbf|pbuf] @ w1^T + b1 -> bf16
// MODE 3: out = hbuf @ w2^T + b2 + x(fp32) -> fp32
// ---------------------------------------------------------------------------
template<int MODE>
__global__ __launch_bounds__(256)
void gemm3(const short* __restrict__ A0, const short* __restrict__ A1,
           const short* __restrict__ Wa, const short* __restrict__ Wb,
           const float* __restrict__ b0, const float* __restrict__ b1v,
           const float* __restrict__ x0, const float* __restrict__ x1,
           short* __restrict__ Cb, float* __restrict__ Cf)
{
    constexpr int K = (MODE == 0 || MODE == 1) ? 256 : 512;

    const int col0 = blockIdx.x * 128;
    const int row0 = blockIdx.y * 128;
    const int tid  = threadIdx.x;
    const int lane = tid & 63, wave = tid >> 6;
    const int ln   = lane & 15, quad = lane >> 4;
    const int wm   = wave & 1,  wn   = wave >> 1;

    __shared__ short As[128 * 40];
    __shared__ short Bs[128 * 40];

    const short* W; int cw;
    if (MODE == 0 && col0 >= 256) { W = Wb; cw = col0 - 256; }
    else                          { W = Wa; cw = col0; }

    const int c = tid & 3;     // k-chunk of 8
    const int r = tid >> 2;    // 0..63

    f32x4 acc[4][4];
    #pragma unroll
    for (int i = 0; i < 4; ++i)
        #pragma unroll
        for (int j = 0; j < 4; ++j) acc[i][j] = {0.f, 0.f, 0.f, 0.f};

    for (int k0 = 0; k0 < K; k0 += 32) {
        #pragma unroll
        for (int g = 0; g < 2; ++g) {
            int rr = r + g * 64;
            int row = row0 + rr, kk = k0 + c * 8;
            const short* ap;
            if (MODE == 2) ap = (kk < 256) ? A0 + (size_t)row * 256 + kk
                                           : A1 + (size_t)row * 256 + (kk - 256);
            else           ap = A0 + (size_t)row * K + kk;
            *(short8*)&As[rr * 40 + c * 8] = *(const short8*)ap;
            *(short8*)&Bs[rr * 40 + c * 8] =
                *(const short8*)(W + (size_t)(cw + rr) * K + kk);
        }
        __syncthreads();

        short8 a[4], b[4];
        #pragma unroll
        for (int mi = 0; mi < 4; ++mi)
            a[mi] = *(const short8*)&As[(wm * 64 + mi * 16 + ln) * 40 + quad * 8];
        #pragma unroll
        for (int nj = 0; nj < 4; ++nj)
            b[nj] = *(const short8*)&Bs[(wn * 64 + nj * 16 + ln) * 40 + quad * 8];
        #pragma unroll
        for (int mi = 0; mi < 4; ++mi)
            #pragma unroll
            for (int nj = 0; nj < 4; ++nj)
                acc[mi][nj] = __builtin_amdgcn_mfma_f32_16x16x32_bf16(
                                  a[mi], b[nj], acc[mi][nj], 0, 0, 0);
        __syncthreads();
    }

    #pragma unroll
    for (int mi = 0; mi < 4; ++mi)
        #pragma unroll
        for (int nj = 0; nj < 4; ++nj)
            #pragma unroll
            for (int rr = 0; rr < 4; ++rr) {
                int row = row0 + wm * 64 + mi * 16 + quad * 4 + rr;
                int col = col0 + wn * 64 + nj * 16 + ln;
                float v = acc[mi][nj][rr];
                if (MODE == 0) {
                    v = (col < 256) ? (v + b0[col]) * SQS : (v + b1v[col - 256]);
                    Cb[(size_t)row * 512 + col] = f2b(v);
                } else if (MODE == 1) {
                    Cb[(size_t)row * 256 + col] = f2b(v + b0[col]);
                } else if (MODE == 2) {
                    Cb[(size_t)row * 512 + col] = f2b(v + b0[col]);
                } else {
                    const float* xr = (row < ROWS ? x0 + (size_t)row * 256
                                                  : x1 + (size_t)(row - ROWS) * 256);
                    Cf[(size_t)row * 256 + col] = v + b0[col] + xr[col];
                }
            }
}

// ---------------------------------------------------------------------------
// Build global V^T: vtbuf[((g*4+h)*64 + d)][tok%2048], g = tok/2048.
// Per block: one 64-token x 64-d tile of one (g,h). LDS stride 76.
// ---------------------------------------------------------------------------
__global__ __launch_bounds__(256)
void vtrans(const short* __restrict__ proj, short* __restrict__ vtbuf)
{
    const int tt = blockIdx.x;         // 0..31 (64-token tiles)
    const int gh = blockIdx.y;         // 0..31: g = gh>>2, h = gh&3
    const int g = gh >> 2, h = gh & 3;
    const int tid = threadIdx.x;
    const int tok0 = g * 2048 + tt * 64;

    __shared__ short Ls[64 * 76];

    {   // stage 64 tok x 64 d (coalesced short4 reads)
        int c4 = tid & 15, r0 = tid >> 4;
        #pragma unroll
        for (int gg = 0; gg < 4; ++gg) {
            int r = r0 + gg * 16;
            *(short4v*)&Ls[r * 76 + c4 * 4] =
                *(const short4v*)(proj + (size_t)(tok0 + r) * 512 + 256 + h * 64 + c4 * 4);
        }
    }
    __syncthreads();

    #pragma unroll
    for (int p = 0; p < 2; ++p) {
        int ch = tid + p * 256;        // 512 chunks: d = ch>>3, tok chunk = ch&7
        int d = ch >> 3, cc = ch & 7;
        short8 s;
        #pragma unroll
        for (int j = 0; j < 8; ++j) s[j] = Ls[(cc * 8 + j) * 76 + d];
        *(short8*)(vtbuf + (size_t)((g * 4 + h) * 64 + d) * 2048 + tt * 64 + cc * 8) = s;
    }
}

// ---------------------------------------------------------------------------
// MFMA flash cross-attention v3. proj bf16 [tok,512] = [qk*SQS | v].
// LDS: QP (Q tile, reused for P — same-wave rows, no barrier), KS, VT staged
// from vtbuf. 36.9 KB -> 4 blocks/CU. 2 barriers per KV iter. exp2 softmax.
// ---------------------------------------------------------------------------
__global__ __launch_bounds__(256)
void attn3(const short* __restrict__ proj, const short* __restrict__ vtbuf,
           short* __restrict__ mbuf)
{
    const int qt  = blockIdx.x;            // 0..15
    const int b   = blockIdx.y >> 2, h = blockIdx.y & 3;
    const int dir = blockIdx.z;
    const int tid = threadIdx.x;
    const int lane = tid & 63, wave = tid >> 6;
    const int ln   = lane & 15, quad = lane >> 4;

    const int qbase = dir * ROWS + b * 2048;
    const int kbase = (1 - dir) * ROWS + b * 2048;
    const int vg    = ((1 - dir) * 4 + b) * 4 + h;   // row group in vtbuf

    __shared__ short QP[128 * 72];   // Q tile, then P tile
    __shared__ short KS[64 * 72];
    __shared__ short VT[64 * 72];    // VT[d][kv]

    {   // load Q tile 128x64
        int c = tid & 7, r0 = tid >> 3;
        #pragma unroll
        for (int g = 0; g < 4; ++g) {
            int r = r0 + g * 32;
            *(short8*)&QP[r * 72 + c * 8] =
                *(const short8*)(proj + (size_t)(qbase + qt * 128 + r) * 512 + h * 64 + c * 8);
        }
    }
    __syncthreads();

    short8 qf[2][2];
    #pragma unroll
    for (int mi = 0; mi < 2; ++mi)
        #pragma unroll
        for (int ks = 0; ks < 2; ++ks)
            qf[mi][ks] = *(const short8*)&QP[(wave * 32 + mi * 16 + ln) * 72
                                             + ks * 32 + quad * 8];

    f32x4 O[2][4];
    float mrun[2][4], lrun[2][4];
    #pragma unroll
    for (int mi = 0; mi < 2; ++mi) {
        #pragma unroll
        for (int nj = 0; nj < 4; ++nj) O[mi][nj] = {0.f, 0.f, 0.f, 0.f};
        #pragma unroll
        for (int r = 0; r < 4; ++r) { mrun[mi][r] = -1e30f; lrun[mi][r] = 0.f; }
    }

    {   // stage tile 0
        int c = tid & 7, r0 = tid >> 3;
        #pragma unroll
        for (int g = 0; g < 2; ++g) {
            int r = r0 + g * 32;
            *(short8*)&KS[r * 72 + c * 8] =
                *(const short8*)(proj + (size_t)(kbase + r) * 512 + h * 64 + c * 8);
            *(short8*)&VT[r * 72 + c * 8] =
                *(const short8*)(vtbuf + (size_t)(vg * 64 + r) * 2048 + c * 8);
        }
    }

    for (int j0 = 0; j0 < 2048; j0 += 64) {
        __syncthreads();   // staging visible

        // S = Q @ K^T
        f32x4 S[2][4];
        #pragma unroll
        for (int mi = 0; mi < 2; ++mi)
            #pragma unroll
            for (int nj = 0; nj < 4; ++nj) S[mi][nj] = {0.f, 0.f, 0.f, 0.f};
        #pragma unroll
        for (int nj = 0; nj < 4; ++nj) {
            short8 k0 = *(const short8*)&KS[(nj * 16 + ln) * 72 + quad * 8];
            short8 k1 = *(const short8*)&KS[(nj * 16 + ln) * 72 + 32 + quad * 8];
            #pragma unroll
            for (int mi = 0; mi < 2; ++mi) {
                S[mi][nj] = __builtin_amdgcn_mfma_f32_16x16x32_bf16(
                                qf[mi][0], k0, S[mi][nj], 0, 0, 0);
                S[mi][nj] = __builtin_amdgcn_mfma_f32_16x16x32_bf16(
                                qf[mi][1], k1, S[mi][nj], 0, 0, 0);
            }
        }

        // online softmax in exp2 domain (row = quad*4+r, cols = 4 nj x 16 ln)
        float aexp[2][4], mb[2][4];
        #pragma unroll
        for (int mi = 0; mi < 2; ++mi)
            #pragma unroll
            for (int r = 0; r < 4; ++r) {
                float t = S[mi][0][r];
                #pragma unroll
                for (int nj = 1; nj < 4; ++nj) t = fmaxf(t, S[mi][nj][r]);
                t = fmaxf(t, __shfl_xor(t, 1));
                t = fmaxf(t, __shfl_xor(t, 2));
                t = fmaxf(t, __shfl_xor(t, 4));
                t = fmaxf(t, __shfl_xor(t, 8));
                float mn = fmaxf(mrun[mi][r], t);
                aexp[mi][r] = exp2f((mrun[mi][r] - mn) * L2E);
                mrun[mi][r] = mn;
                mb[mi][r] = mn * L2E;
            }
        float rs[2][4] = {};
        #pragma unroll
        for (int mi = 0; mi < 2; ++mi)
            #pragma unroll
            for (int nj = 0; nj < 4; ++nj)
                #pragma unroll
                for (int r = 0; r < 4; ++r) {
                    float p = exp2f(fmaf(S[mi][nj][r], L2E, -mb[mi][r]));
                    rs[mi][r] += p;
                    QP[(wave * 32 + mi * 16 + quad * 4 + r) * 72 + nj * 16 + ln] = f2b(p);
                }
        #pragma unroll
        for (int mi = 0; mi < 2; ++mi)
            #pragma unroll
            for (int r = 0; r < 4; ++r) {
                float t = rs[mi][r];
                t += __shfl_xor(t, 1);
                t += __shfl_xor(t, 2);
                t += __shfl_xor(t, 4);
                t += __shfl_xor(t, 8);
                lrun[mi][r] = lrun[mi][r] * aexp[mi][r] + t;
            }
        #pragma unroll
        for (int mi = 0; mi < 2; ++mi)
            #pragma unroll
            for (int nj = 0; nj < 4; ++nj)
                #pragma unroll
                for (int r = 0; r < 4; ++r) O[mi][nj][r] *= aexp[mi][r];

        // O += P @ V   (P rows are this wave's own — lgkmcnt ordering suffices)
        #pragma unroll
        for (int nj = 0; nj < 4; ++nj) {
            short8 v0 = *(const short8*)&VT[(nj * 16 + ln) * 72 + quad * 8];
            short8 v1 = *(const short8*)&VT[(nj * 16 + ln) * 72 + 32 + quad * 8];
            #pragma unroll
            for (int mi = 0; mi < 2; ++mi) {
                short8 p0 = *(const short8*)&QP[(wave * 32 + mi * 16 + ln) * 72 + quad * 8];
                short8 p1 = *(const short8*)&QP[(wave * 32 + mi * 16 + ln) * 72 + 32 + quad * 8];
                O[mi][nj] = __builtin_amdgcn_mfma_f32_16x16x32_bf16(
                                p0, v0, O[mi][nj], 0, 0, 0);
                O[mi][nj] = __builtin_amdgcn_mfma_f32_16x16x32_bf16(
                                p1, v1, O[mi][nj], 0, 0, 0);
            }
        }
        __syncthreads();   // all LDS reads done -> safe to restage

        if (j0 + 64 < 2048) {
            int c = tid & 7, r0 = tid >> 3;
            #pragma unroll
            for (int g = 0; g < 2; ++g) {
                int r = r0 + g * 32;
                *(short8*)&KS[r * 72 + c * 8] =
                    *(const short8*)(proj + (size_t)(kbase + j0 + 64 + r) * 512 + h * 64 + c * 8);
                *(short8*)&VT[r * 72 + c * 8] =
                    *(const short8*)(vtbuf + (size_t)(vg * 64 + r) * 2048 + j0 + 64 + c * 8);
            }
        }
    }

    #pragma unroll
    for (int mi = 0; mi < 2; ++mi)
        #pragma unroll
        for (int r = 0; r < 4; ++r) {
            float linv = 1.f / lrun[mi][r];
            #pragma unroll
            for (int nj = 0; nj < 4; ++nj) {
                int row = qbase + qt * 128 + wave * 32 + mi * 16 + quad * 4 + r;
                mbuf[(size_t)row * 256 + h * 64 + nj * 16 + ln] =
                    f2b(O[mi][nj][r] * linv);
            }
        }
}

// ---------------------------------------------------------------------------
// In-place LayerNorm(512) + exact GELU on bf16 rows. One wave per row.
// ---------------------------------------------------------------------------
__global__ __launch_bounds__(256)
void ln_gelu2(short* __restrict__ h, const float* __restrict__ gamma,
              const float* __restrict__ beta)
{
    const int wave = threadIdx.x >> 6, lane = threadIdx.x & 63;
    const int row = blockIdx.x * 4 + wave;
    short* hp = h + (size_t)row * 512 + lane * 8;
    short8 sv = *(const short8*)hp;
    float v[8], s1 = 0.f, s2 = 0.f;
    #pragma unroll
    for (int i = 0; i < 8; ++i) { v[i] = b2f(sv[i]); s1 += v[i]; s2 += v[i] * v[i]; }
    #pragma unroll
    for (int off = 32; off; off >>= 1) {
        s1 += __shfl_xor(s1, off);
        s2 += __shfl_xor(s2, off);
    }
    float mean = s1 * (1.f / 512.f);
    float var  = s2 * (1.f / 512.f) - mean * mean;
    float rstd = rsqrtf(var + 1e-5f);
    #pragma unroll
    for (int i = 0; i < 8; ++i) {
        int o = lane * 8 + i;
        float y = (v[i] - mean) * rstd * gamma[o] + beta[o];
        sv[i] = f2b(0.5f * y * (1.f + erff(y * 0.70710678118654752f)));
    }
    *(short8*)hp = sv;
}

// ---------------------------------------------------------------------------
extern "C" void kernel_launch(void* const* d_in, const int* in_sizes, int n_in,
                              void* d_out, int out_size, void* d_ws, size_t ws_size,
                              hipStream_t stream)
{
    const float* x0    = (const float*)d_in[0];
    const float* x1    = (const float*)d_in[1];
    const float* Wqk   = (const float*)d_in[2];
    const float* bqk   = (const float*)d_in[3];
    const float* Wv    = (const float*)d_in[4];
    const float* bv    = (const float*)d_in[5];
    const float* Wp    = (const float*)d_in[6];
    const float* bp    = (const float*)d_in[7];
    const float* W1    = (const float*)d_in[8];
    const float* b1    = (const float*)d_in[9];
    const float* gamma = (const float*)d_in[10];
    const float* beta  = (const float*)d_in[11];
    const float* W2    = (const float*)d_in[12];
    const float* b2    = (const float*)d_in[13];
    float* out = (float*)d_out;

    char* ws = (char*)d_ws;
    const size_t MB = 1024 * 1024;
    short* xbf  = (short*)ws;                    // [16384,256]  8 MB
    short* proj = (short*)(ws + 8  * MB);        // [16384,512] 16 MB (-> hbuf)
    short* vtb  = (short*)(ws + 24 * MB);        // [2048,2048]  8 MB (-> pbuf)
    short* mbuf = (short*)(ws + 32 * MB);        // [16384,256]  8 MB
    short* wq   = (short*)(ws + 40 * MB);        // weights ~1.2 MB
    short* wv   = wq + 65536;
    short* wp   = wv + 65536;
    short* w1   = wp + 65536;
    short* w2   = w1 + 262144;
    short* pbuf = vtb;                           // overlays vtbuf (dead after attn)
    short* hbuf = proj;                          // overlays proj  (dead after attn)

    cvt_all<<<dim3(2048, 7), 256, 0, stream>>>(x0, x1, Wqk, Wv, Wp, W1, W2,
                                               xbf, wq, wv, wp, w1, w2);
    gemm3<0><<<dim3(4, 128), 256, 0, stream>>>(xbf, nullptr, wq, wv, bqk, bv,
                                               nullptr, nullptr, proj, nullptr);
    vtrans<<<dim3(32, 32), 256, 0, stream>>>(proj, vtb);
    attn3<<<dim3(16, 16, 2), 256, 0, stream>>>(proj, vtb, mbuf);
    gemm3<1><<<dim3(2, 128), 256, 0, stream>>>(mbuf, nullptr, wp, nullptr, bp, nullptr,
                                               nullptr, nullptr, pbuf, nullptr);
    gemm3<2><<<dim3(4, 128), 256, 0, stream>>>(xbf, pbuf, w1, nullptr, b1, nullptr,
                                               nullptr, nullptr, hbuf, nullptr);
    ln_gelu2<<<4096, 256, 0, stream>>>(hbuf, gamma, beta);
    gemm3<3><<<dim3(2, 128), 256, 0, stream>>>(hbuf, nullptr, w2, nullptr, b2, nullptr,
                                               x0, x1, nullptr, out);
}

// Round 6
// 282.884 us; speedup vs baseline: 9.2385x; 1.1413x over previous
//
#include <hip/hip_runtime.h>
#include <hip/hip_bf16.h>
#include <math.h>

typedef __hip_bfloat16 hbf;
typedef __attribute__((ext_vector_type(8))) short short8;   // 8 bf16
typedef __attribute__((ext_vector_type(4))) short short4v;  // 4 bf16
typedef __attribute__((ext_vector_type(4))) float f32x4;

#define ROWS 8192
#define SQS  0.35355339059327373f   // sqrt(DH^-0.5)
#define L2E  1.4426950408889634f

__device__ __forceinline__ short f2b(float f) {
    union { hbf h; short s; } u; u.h = __float2bfloat16(f); return u.s;
}
__device__ __forceinline__ float b2f(short s) {
    union { unsigned u; float f; } x;
    x.u = ((unsigned)(unsigned short)s) << 16; return x.f;
}

// ---------------------------------------------------------------------------
// fp32 -> bf16 bulk convert. blockIdx.y selects source; one float4 per thread.
// ---------------------------------------------------------------------------
__global__ __launch_bounds__(256)
void cvt_all(const float* __restrict__ x0, const float* __restrict__ x1,
             const float* __restrict__ Wqk, const float* __restrict__ Wv,
             const float* __restrict__ Wp, const float* __restrict__ W1,
             const float* __restrict__ W2,
             short* __restrict__ xbf, short* __restrict__ wq,
             short* __restrict__ wv, short* __restrict__ wp,
             short* __restrict__ w1, short* __restrict__ w2)
{
    const int y = blockIdx.y;
    const float* src; short* dst; int n;  // n in float4 units
    switch (y) {
    case 0: src = x0;  dst = xbf;               n = 524288; break;
    case 1: src = x1;  dst = xbf + 8192 * 256;  n = 524288; break;
    case 2: src = Wqk; dst = wq;                n = 16384;  break;
    case 3: src = Wv;  dst = wv;                n = 16384;  break;
    case 4: src = Wp;  dst = wp;                n = 16384;  break;
    case 5: src = W1;  dst = w1;                n = 65536;  break;
    default: src = W2; dst = w2;                n = 32768;  break;
    }
    int i = blockIdx.x * 256 + threadIdx.x;
    if (i >= n) return;
    float4 f = ((const float4*)src)[i];
    short4v s; s[0] = f2b(f.x); s[1] = f2b(f.y); s[2] = f2b(f.z); s[3] = f2b(f.w);
    *(short4v*)(dst + (size_t)i * 4) = s;
}

// ---------------------------------------------------------------------------
// MFMA GEMM, all-bf16, C^T fragment orientation: D[wcol][token] via
// mfma(Wfrag, TokFrag) -> epilogue writes 4 consecutive wcols per lane
// (vector stores). 128x128 block, 4 waves x (4x4) tiles, BK=32.
// MODE 0: proj = xbf @ [wq;wv]^T, +bias, qk-half *SQS -> bf16
// MODE 1: p = mbuf @ wp^T + bp -> bf16
// MODE 2: h = [xbf|pbuf] @ w1^T + b1 -> bf16
// MODE 3: out = hbuf @ w2^T + b2 + x(fp32) -> fp32
// ---------------------------------------------------------------------------
template<int MODE>
__global__ __launch_bounds__(256)
void gemm4(const short* __restrict__ A0, const short* __restrict__ A1,
           const short* __restrict__ Wa, const short* __restrict__ Wb,
           const float* __restrict__ b0, const float* __restrict__ b1v,
           const float* __restrict__ x0, const float* __restrict__ x1,
           short* __restrict__ Cb, float* __restrict__ Cf)
{
    constexpr int K = (MODE == 0 || MODE == 1) ? 256 : 512;

    const int col0 = blockIdx.x * 128;
    const int row0 = blockIdx.y * 128;
    const int tid  = threadIdx.x;
    const int lane = tid & 63, wave = tid >> 6;
    const int ln   = lane & 15, quad = lane >> 4;
    const int wm   = wave & 1,  wn   = wave >> 1;

    __shared__ short As[128 * 40];
    __shared__ short Bs[128 * 40];

    const short* W; int cw;
    const float* bias; int boff;
    if (MODE == 0 && col0 >= 256) { W = Wb; cw = col0 - 256; bias = b1v; boff = col0 - 256; }
    else                          { W = Wa; cw = col0;       bias = b0;  boff = col0; }

    const int c = tid & 3;     // k-chunk of 8
    const int r = tid >> 2;    // 0..63

    f32x4 acc[4][4];
    #pragma unroll
    for (int i = 0; i < 4; ++i)
        #pragma unroll
        for (int j = 0; j < 4; ++j) acc[i][j] = {0.f, 0.f, 0.f, 0.f};

    for (int k0 = 0; k0 < K; k0 += 32) {
        #pragma unroll
        for (int g = 0; g < 2; ++g) {
            int rr = r + g * 64;
            int row = row0 + rr, kk = k0 + c * 8;
            const short* ap;
            if (MODE == 2) ap = (kk < 256) ? A0 + (size_t)row * 256 + kk
                                           : A1 + (size_t)row * 256 + (kk - 256);
            else           ap = A0 + (size_t)row * K + kk;
            *(short8*)&As[rr * 40 + c * 8] = *(const short8*)ap;
            *(short8*)&Bs[rr * 40 + c * 8] =
                *(const short8*)(W + (size_t)(cw + rr) * K + kk);
        }
        __syncthreads();

        short8 a[4], b[4];
        #pragma unroll
        for (int mi = 0; mi < 4; ++mi)
            a[mi] = *(const short8*)&As[(wm * 64 + mi * 16 + ln) * 40 + quad * 8];
        #pragma unroll
        for (int nj = 0; nj < 4; ++nj)
            b[nj] = *(const short8*)&Bs[(wn * 64 + nj * 16 + ln) * 40 + quad * 8];
        #pragma unroll
        for (int mi = 0; mi < 4; ++mi)
            #pragma unroll
            for (int nj = 0; nj < 4; ++nj)
                acc[mi][nj] = __builtin_amdgcn_mfma_f32_16x16x32_bf16(
                                  b[nj], a[mi], acc[mi][nj], 0, 0, 0);
        __syncthreads();
    }

    // epilogue: frag(mi,nj): col(lane) = token = row0+wm*64+mi*16+ln,
    //                        row(reg)  = wcol  = col0+wn*64+nj*16+quad*4+r
    #pragma unroll
    for (int nj = 0; nj < 4; ++nj) {
        int wrel = wn * 64 + nj * 16 + quad * 4;         // rel to boff
        float4 bb = *(const float4*)(bias + boff + wrel);
        int wcol = col0 + wrel;
        #pragma unroll
        for (int mi = 0; mi < 4; ++mi) {
            int tok = row0 + wm * 64 + mi * 16 + ln;
            f32x4 v = acc[mi][nj];
            if (MODE == 0) {
                float sc = (col0 < 256) ? SQS : 1.f;
                short4v o;
                o[0] = f2b((v[0] + bb.x) * sc); o[1] = f2b((v[1] + bb.y) * sc);
                o[2] = f2b((v[2] + bb.z) * sc); o[3] = f2b((v[3] + bb.w) * sc);
                *(short4v*)(Cb + (size_t)tok * 512 + wcol) = o;
            } else if (MODE == 1) {
                short4v o;
                o[0] = f2b(v[0] + bb.x); o[1] = f2b(v[1] + bb.y);
                o[2] = f2b(v[2] + bb.z); o[3] = f2b(v[3] + bb.w);
                *(short4v*)(Cb + (size_t)tok * 256 + wcol) = o;
            } else if (MODE == 2) {
                short4v o;
                o[0] = f2b(v[0] + bb.x); o[1] = f2b(v[1] + bb.y);
                o[2] = f2b(v[2] + bb.z); o[3] = f2b(v[3] + bb.w);
                *(short4v*)(Cb + (size_t)tok * 512 + wcol) = o;
            } else {
                const float* xr = (tok < ROWS ? x0 + (size_t)tok * 256
                                              : x1 + (size_t)(tok - ROWS) * 256);
                float4 rv = *(const float4*)(xr + wcol);
                float4 o;
                o.x = v[0] + bb.x + rv.x; o.y = v[1] + bb.y + rv.y;
                o.z = v[2] + bb.z + rv.z; o.w = v[3] + bb.w + rv.w;
                *(float4*)(Cf + (size_t)tok * 256 + wcol) = o;
            }
        }
    }
}

// ---------------------------------------------------------------------------
// Build global V^T: vtbuf[((g*4+h)*64 + d)][tok%2048], g = tok/2048.
// ---------------------------------------------------------------------------
__global__ __launch_bounds__(256)
void vtrans(const short* __restrict__ proj, short* __restrict__ vtbuf)
{
    const int tt = blockIdx.x;         // 0..31 (64-token tiles)
    const int gh = blockIdx.y;         // 0..31
    const int g = gh >> 2, h = gh & 3;
    const int tid = threadIdx.x;
    const int tok0 = g * 2048 + tt * 64;

    __shared__ short Ls[64 * 76];

    {
        int c4 = tid & 15, r0 = tid >> 4;
        #pragma unroll
        for (int gg = 0; gg < 4; ++gg) {
            int r = r0 + gg * 16;
            *(short4v*)&Ls[r * 76 + c4 * 4] =
                *(const short4v*)(proj + (size_t)(tok0 + r) * 512 + 256 + h * 64 + c4 * 4);
        }
    }
    __syncthreads();

    #pragma unroll
    for (int p = 0; p < 2; ++p) {
        int ch = tid + p * 256;
        int d = ch >> 3, cc = ch & 7;
        short8 s;
        #pragma unroll
        for (int j = 0; j < 8; ++j) s[j] = Ls[(cc * 8 + j) * 76 + d];
        *(short8*)(vtbuf + (size_t)((g * 4 + h) * 64 + d) * 2048 + tt * 64 + cc * 8) = s;
    }
}

// ---------------------------------------------------------------------------
// MFMA flash cross-attention v4 — S^T formulation.
// S^T = mfma(Kfrag, Qfrag): col=q (lane), row=kv (reg) -> softmax reduction
// is in-lane + 2 shuffles; m/l/alpha are one scalar per lane; P lands in
// [q][kv] layout with vector LDS writes. O^T = mfma(VTfrag, Pfrag).
// Q-tile 64 (grid 1024 blocks), 4 waves x 16 q rows. QP aliased Q->P
// (each wave owns its 16 rows). LDS 27.6 KB.
// ---------------------------------------------------------------------------
__global__ __launch_bounds__(256)
void attn4(const short* __restrict__ proj, const short* __restrict__ vtbuf,
           short* __restrict__ mbuf)
{
    const int qt  = blockIdx.x;            // 0..31
    const int b   = blockIdx.y >> 2, h = blockIdx.y & 3;
    const int dir = blockIdx.z;
    const int tid = threadIdx.x;
    const int lane = tid & 63, wave = tid >> 6;
    const int ln   = lane & 15, quad = lane >> 4;

    const int qbase = dir * ROWS + b * 2048;
    const int kbase = (1 - dir) * ROWS + b * 2048;
    const int vg    = ((1 - dir) * 4 + b) * 4 + h;

    __shared__ short QP[64 * 72];   // Q tile, then P tile (per-wave-private rows)
    __shared__ short KS[64 * 72];
    __shared__ short VT[64 * 72];   // VT[d][kv]

    const int c = tid & 7, r0 = tid >> 3;
    #pragma unroll
    for (int g = 0; g < 2; ++g) {
        int r = r0 + g * 32;
        *(short8*)&QP[r * 72 + c * 8] =
            *(const short8*)(proj + (size_t)(qbase + qt * 64 + r) * 512 + h * 64 + c * 8);
        *(short8*)&KS[r * 72 + c * 8] =
            *(const short8*)(proj + (size_t)(kbase + r) * 512 + h * 64 + c * 8);
        *(short8*)&VT[r * 72 + c * 8] =
            *(const short8*)(vtbuf + (size_t)(vg * 64 + r) * 2048 + c * 8);
    }
    __syncthreads();

    const int qrow = wave * 16 + ln;               // this lane's q row (B-frag n)
    short8 qf0 = *(const short8*)&QP[qrow * 72 + quad * 8];
    short8 qf1 = *(const short8*)&QP[qrow * 72 + 32 + quad * 8];

    f32x4 Ot[4];
    #pragma unroll
    for (int dt = 0; dt < 4; ++dt) Ot[dt] = {0.f, 0.f, 0.f, 0.f};
    float mrun = -3.0e38f, lrun = 0.f;

    for (int j0 = 0; j0 < 2048; j0 += 64) {
        // S^T = K @ Q^T : 4 kv-tiles x (this wave's q-tile)
        f32x4 St[4];
        #pragma unroll
        for (int t = 0; t < 4; ++t) {
            short8 k0 = *(const short8*)&KS[(t * 16 + ln) * 72 + quad * 8];
            short8 k1 = *(const short8*)&KS[(t * 16 + ln) * 72 + 32 + quad * 8];
            f32x4 z = {0.f, 0.f, 0.f, 0.f};
            z = __builtin_amdgcn_mfma_f32_16x16x32_bf16(k0, qf0, z, 0, 0, 0);
            St[t] = __builtin_amdgcn_mfma_f32_16x16x32_bf16(k1, qf1, z, 0, 0, 0);
        }

        // online softmax over kv (in-lane + xor16/xor32), state per lane
        float mx = St[0][0];
        #pragma unroll
        for (int t = 0; t < 4; ++t)
            #pragma unroll
            for (int r = 0; r < 4; ++r) mx = fmaxf(mx, St[t][r]);
        mx = fmaxf(mx, __shfl_xor(mx, 16));
        mx = fmaxf(mx, __shfl_xor(mx, 32));
        float nm = fmaxf(mrun, mx);
        float al = exp2f((mrun - nm) * L2E);
        float nl = nm * L2E;
        mrun = nm;

        float ss = 0.f;
        #pragma unroll
        for (int t = 0; t < 4; ++t) {
            short4v pv;
            #pragma unroll
            for (int r = 0; r < 4; ++r) {
                float p = exp2f(fmaf(St[t][r], L2E, -nl));
                ss += p;
                pv[r] = f2b(p);
            }
            *(short4v*)&QP[qrow * 72 + t * 16 + quad * 4] = pv;
        }
        ss += __shfl_xor(ss, 16);
        ss += __shfl_xor(ss, 32);
        lrun = lrun * al + ss;
        #pragma unroll
        for (int dt = 0; dt < 4; ++dt)
            #pragma unroll
            for (int r = 0; r < 4; ++r) Ot[dt][r] *= al;

        // O^T += V^T @ P^T (P rows are this wave's own; in-wave LDS ordering)
        short8 p0 = *(const short8*)&QP[qrow * 72 + quad * 8];
        short8 p1 = *(const short8*)&QP[qrow * 72 + 32 + quad * 8];
        #pragma unroll
        for (int dt = 0; dt < 4; ++dt) {
            short8 v0 = *(const short8*)&VT[(dt * 16 + ln) * 72 + quad * 8];
            short8 v1 = *(const short8*)&VT[(dt * 16 + ln) * 72 + 32 + quad * 8];
            Ot[dt] = __builtin_amdgcn_mfma_f32_16x16x32_bf16(v0, p0, Ot[dt], 0, 0, 0);
            Ot[dt] = __builtin_amdgcn_mfma_f32_16x16x32_bf16(v1, p1, Ot[dt], 0, 0, 0);
        }
        __syncthreads();   // KS/VT reads done

        if (j0 + 64 < 2048) {
            #pragma unroll
            for (int g = 0; g < 2; ++g) {
                int r = r0 + g * 32;
                *(short8*)&KS[r * 72 + c * 8] =
                    *(const short8*)(proj + (size_t)(kbase + j0 + 64 + r) * 512 + h * 64 + c * 8);
                *(short8*)&VT[r * 72 + c * 8] =
                    *(const short8*)(vtbuf + (size_t)(vg * 64 + r) * 2048 + j0 + 64 + c * 8);
            }
        }
        __syncthreads();   // staging visible
    }

    // epilogue: O^T frag: col=q(lane)=qrow, row=d=dt*16+quad*4+r (contiguous)
    float li = 1.f / lrun;
    int tok = qbase + qt * 64 + qrow;
    #pragma unroll
    for (int dt = 0; dt < 4; ++dt) {
        short4v o;
        #pragma unroll
        for (int r = 0; r < 4; ++r) o[r] = f2b(Ot[dt][r] * li);
        *(short4v*)(mbuf + (size_t)tok * 256 + h * 64 + dt * 16 + quad * 4) = o;
    }
}

// ---------------------------------------------------------------------------
// In-place LayerNorm(512) + exact GELU on bf16 rows. One wave per row.
// ---------------------------------------------------------------------------
__global__ __launch_bounds__(256)
void ln_gelu2(short* __restrict__ h, const float* __restrict__ gamma,
              const float* __restrict__ beta)
{
    const int wave = threadIdx.x >> 6, lane = threadIdx.x & 63;
    const int row = blockIdx.x * 4 + wave;
    short* hp = h + (size_t)row * 512 + lane * 8;
    short8 sv = *(const short8*)hp;
    float v[8], s1 = 0.f, s2 = 0.f;
    #pragma unroll
    for (int i = 0; i < 8; ++i) { v[i] = b2f(sv[i]); s1 += v[i]; s2 += v[i] * v[i]; }
    #pragma unroll
    for (int off = 32; off; off >>= 1) {
        s1 += __shfl_xor(s1, off);
        s2 += __shfl_xor(s2, off);
    }
    float mean = s1 * (1.f / 512.f);
    float var  = s2 * (1.f / 512.f) - mean * mean;
    float rstd = rsqrtf(var + 1e-5f);
    #pragma unroll
    for (int i = 0; i < 8; ++i) {
        int o = lane * 8 + i;
        float y = (v[i] - mean) * rstd * gamma[o] + beta[o];
        sv[i] = f2b(0.5f * y * (1.f + erff(y * 0.70710678118654752f)));
    }
    *(short8*)hp = sv;
}

// ---------------------------------------------------------------------------
extern "C" void kernel_launch(void* const* d_in, const int* in_sizes, int n_in,
                              void* d_out, int out_size, void* d_ws, size_t ws_size,
                              hipStream_t stream)
{
    const float* x0    = (const float*)d_in[0];
    const float* x1    = (const float*)d_in[1];
    const float* Wqk   = (const float*)d_in[2];
    const float* bqk   = (const float*)d_in[3];
    const float* Wv    = (const float*)d_in[4];
    const float* bv    = (const float*)d_in[5];
    const float* Wp    = (const float*)d_in[6];
    const float* bp    = (const float*)d_in[7];
    const float* W1    = (const float*)d_in[8];
    const float* b1    = (const float*)d_in[9];
    const float* gamma = (const float*)d_in[10];
    const float* beta  = (const float*)d_in[11];
    const float* W2    = (const float*)d_in[12];
    const float* b2    = (const float*)d_in[13];
    float* out = (float*)d_out;

    char* ws = (char*)d_ws;
    const size_t MB = 1024 * 1024;
    short* xbf  = (short*)ws;                    // [16384,256]  8 MB
    short* proj = (short*)(ws + 8  * MB);        // [16384,512] 16 MB (-> hbuf)
    short* vtb  = (short*)(ws + 24 * MB);        // [2048,2048]  8 MB (-> pbuf)
    short* mbuf = (short*)(ws + 32 * MB);        // [16384,256]  8 MB
    short* wq   = (short*)(ws + 40 * MB);        // weights ~1.2 MB
    short* wv   = wq + 65536;
    short* wp   = wv + 65536;
    short* w1   = wp + 65536;
    short* w2   = w1 + 262144;
    short* pbuf = vtb;                           // overlays vtbuf (dead after attn)
    short* hbuf = proj;                          // overlays proj  (dead after attn)

    cvt_all<<<dim3(2048, 7), 256, 0, stream>>>(x0, x1, Wqk, Wv, Wp, W1, W2,
                                               xbf, wq, wv, wp, w1, w2);
    gemm4<0><<<dim3(4, 128), 256, 0, stream>>>(xbf, nullptr, wq, wv, bqk, bv,
                                               nullptr, nullptr, proj, nullptr);
    vtrans<<<dim3(32, 32), 256, 0, stream>>>(proj, vtb);
    attn4<<<dim3(32, 16, 2), 256, 0, stream>>>(proj, vtb, mbuf);
    gemm4<1><<<dim3(2, 128), 256, 0, stream>>>(mbuf, nullptr, wp, nullptr, bp, nullptr,
                                               nullptr, nullptr, pbuf, nullptr);
    gemm4<2><<<dim3(4, 128), 256, 0, stream>>>(xbf, pbuf, w1, nullptr, b1, nullptr,
                                               nullptr, nullptr, hbuf, nullptr);
    ln_gelu2<<<4096, 256, 0, stream>>>(hbuf, gamma, beta);
    gemm4<3><<<dim3(2, 128), 256, 0, stream>>>(hbuf, nullptr, w2, nullptr, b2, nullptr,
                                               x0, x1, nullptr, out);
}

// Round 7
// 271.231 us; speedup vs baseline: 9.6354x; 1.0430x over previous
//
#include <hip/hip_runtime.h>
#include <hip/hip_bf16.h>
#include <math.h>

typedef __hip_bfloat16 hbf;
typedef __attribute__((ext_vector_type(8))) short short8;   // 8 bf16
typedef __attribute__((ext_vector_type(4))) short short4v;  // 4 bf16
typedef __attribute__((ext_vector_type(4))) float f32x4;

#define ROWS 8192
#define SQSL 0.4246609001440095f  // sqrt(SCALE * log2(e)) — folded into wq/bqk
#define COFF 24.0f                // static softmax offset (exp2 domain)

__device__ __forceinline__ short f2b(float f) {
    union { hbf h; short s; } u; u.h = __float2bfloat16(f); return u.s;
}
__device__ __forceinline__ float b2f(short s) {
    union { unsigned u; float f; } x;
    x.u = ((unsigned)(unsigned short)s) << 16; return x.f;
}

// ---------------------------------------------------------------------------
// fp32 -> bf16 bulk convert; wq scaled by SQSL (folds qk scale + log2e).
// ---------------------------------------------------------------------------
__global__ __launch_bounds__(256)
void cvt_all(const float* __restrict__ x0, const float* __restrict__ x1,
             const float* __restrict__ Wqk, const float* __restrict__ Wv,
             const float* __restrict__ Wp, const float* __restrict__ W1,
             const float* __restrict__ W2,
             short* __restrict__ xbf, short* __restrict__ wq,
             short* __restrict__ wv, short* __restrict__ wp,
             short* __restrict__ w1, short* __restrict__ w2)
{
    const int y = blockIdx.y;
    const float* src; short* dst; int n; float sc = 1.f;
    switch (y) {
    case 0: src = x0;  dst = xbf;               n = 524288; break;
    case 1: src = x1;  dst = xbf + 8192 * 256;  n = 524288; break;
    case 2: src = Wqk; dst = wq;                n = 16384;  sc = SQSL; break;
    case 3: src = Wv;  dst = wv;                n = 16384;  break;
    case 4: src = Wp;  dst = wp;                n = 16384;  break;
    case 5: src = W1;  dst = w1;                n = 65536;  break;
    default: src = W2; dst = w2;                n = 32768;  break;
    }
    int i = blockIdx.x * 256 + threadIdx.x;
    if (i >= n) return;
    float4 f = ((const float4*)src)[i];
    short4v s;
    s[0] = f2b(f.x * sc); s[1] = f2b(f.y * sc);
    s[2] = f2b(f.z * sc); s[3] = f2b(f.w * sc);
    *(short4v*)(dst + (size_t)i * 4) = s;
}

// ---------------------------------------------------------------------------
// Wc[n][i] = sum_o W1b[n][o] * Wp[o][i]   (W1b = w1[:, 256:512]); bf16 out.
// 512 blocks (n) x 256 threads (i).
// ---------------------------------------------------------------------------
__global__ __launch_bounds__(256)
void wcomp(const short* __restrict__ w1, const short* __restrict__ wp,
           short* __restrict__ wc)
{
    const int n = blockIdx.x, i = threadIdx.x;
    float acc = 0.f;
    for (int k0 = 0; k0 < 256; k0 += 8) {
        short8 a = *(const short8*)(w1 + (size_t)n * 512 + 256 + k0);
        #pragma unroll
        for (int j = 0; j < 8; ++j)
            acc += b2f(a[j]) * b2f(wp[(size_t)(k0 + j) * 256 + i]);
    }
    wc[(size_t)n * 256 + i] = f2b(acc);
}

// bc[n] = b1[n] + sum_o W1b[n][o] * bp[o].  grid 2 x 256.
__global__ __launch_bounds__(256)
void bcomp(const short* __restrict__ w1, const float* __restrict__ bp,
           const float* __restrict__ b1, float* __restrict__ bc)
{
    const int n = blockIdx.x * 256 + threadIdx.x;
    float acc = b1[n];
    for (int k0 = 0; k0 < 256; k0 += 8) {
        short8 a = *(const short8*)(w1 + (size_t)n * 512 + 256 + k0);
        #pragma unroll
        for (int j = 0; j < 8; ++j) acc += b2f(a[j]) * bp[k0 + j];
    }
    bc[n] = acc;
}

// ---------------------------------------------------------------------------
// MFMA GEMM, 64x128 tile, 4 waves x (2x4) frags, BK=32, register-prefetched
// staging, C^T orientation (vector stores).
// MODE 0: proj = xbf @ [wq;wv]^T (+SQSL*bqk | +bv) -> bf16 [tok,512]
// MODE 2: h = [xbf|mbuf] @ [w1a|wc]^T + bc -> bf16 [tok,512]
// MODE 3: out = hbuf @ w2^T + b2 + x -> fp32 [tok,256]
// ---------------------------------------------------------------------------
template<int MODE>
__global__ __launch_bounds__(256)
void gemm5(const short* __restrict__ A0, const short* __restrict__ A1,
           const short* __restrict__ Wa, const short* __restrict__ Wb,
           const float* __restrict__ bias0, const float* __restrict__ bias1,
           const float* __restrict__ x0, const float* __restrict__ x1,
           short* __restrict__ Cb, float* __restrict__ Cf)
{
    constexpr int K = (MODE == 0) ? 256 : 512;
    const int col0 = blockIdx.x * 128;
    const int row0 = blockIdx.y * 64;
    const int tid = threadIdx.x;
    const int lane = tid & 63, wave = tid >> 6;
    const int ln = lane & 15, quad = lane >> 4;
    const int wm = wave & 1, wn = wave >> 1;

    __shared__ short As[64 * 40];
    __shared__ short Bs[128 * 40];

    const int ar = tid >> 2, ac = tid & 3;

    f32x4 acc[2][4];
    #pragma unroll
    for (int i = 0; i < 2; ++i)
        #pragma unroll
        for (int j = 0; j < 4; ++j) acc[i][j] = {0.f, 0.f, 0.f, 0.f};

    auto aptr = [&](int kk) -> const short* {
        int row = row0 + ar;
        if (MODE == 2) return (kk < 256) ? A0 + (size_t)row * 256 + kk
                                         : A1 + (size_t)row * 256 + (kk - 256);
        return A0 + (size_t)row * K + kk;
    };
    auto wptr = [&](int rr, int kk) -> const short* {
        int n = col0 + rr;
        if (MODE == 0) {
            if (col0 < 256) return Wa + (size_t)n * 256 + kk;
            return Wb + (size_t)(n - 256) * 256 + kk;
        } else if (MODE == 2) {
            return (kk < 256) ? Wa + (size_t)n * 512 + kk
                              : Wb + (size_t)n * 256 + (kk - 256);
        } else {
            return Wa + (size_t)n * 512 + kk;
        }
    };

    short8 aR  = *(const short8*)aptr(ac * 8);
    short8 bR0 = *(const short8*)wptr(ar, ac * 8);
    short8 bR1 = *(const short8*)wptr(ar + 64, ac * 8);

    for (int k0 = 0; k0 < K; k0 += 32) {
        *(short8*)&As[ar * 40 + ac * 8] = aR;
        *(short8*)&Bs[ar * 40 + ac * 8] = bR0;
        *(short8*)&Bs[(ar + 64) * 40 + ac * 8] = bR1;
        __syncthreads();

        if (k0 + 32 < K) {
            aR  = *(const short8*)aptr(k0 + 32 + ac * 8);
            bR0 = *(const short8*)wptr(ar, k0 + 32 + ac * 8);
            bR1 = *(const short8*)wptr(ar + 64, k0 + 32 + ac * 8);
        }

        short8 a[2], b[4];
        #pragma unroll
        for (int mi = 0; mi < 2; ++mi)
            a[mi] = *(const short8*)&As[(wm * 32 + mi * 16 + ln) * 40 + quad * 8];
        #pragma unroll
        for (int nj = 0; nj < 4; ++nj)
            b[nj] = *(const short8*)&Bs[(wn * 64 + nj * 16 + ln) * 40 + quad * 8];
        #pragma unroll
        for (int mi = 0; mi < 2; ++mi)
            #pragma unroll
            for (int nj = 0; nj < 4; ++nj)
                acc[mi][nj] = __builtin_amdgcn_mfma_f32_16x16x32_bf16(
                                  b[nj], a[mi], acc[mi][nj], 0, 0, 0);
        __syncthreads();
    }

    #pragma unroll
    for (int nj = 0; nj < 4; ++nj) {
        int wrel = wn * 64 + nj * 16 + quad * 4;
        int wcol = col0 + wrel;
        const float* bias = (MODE == 0 && col0 >= 256) ? bias1 : bias0;
        int boff = (MODE == 0 && col0 >= 256) ? (wcol - 256) : wcol;
        float4 bb = *(const float4*)(bias + boff);
        #pragma unroll
        for (int mi = 0; mi < 2; ++mi) {
            int tok = row0 + wm * 32 + mi * 16 + ln;
            f32x4 v = acc[mi][nj];
            if (MODE == 0) {
                float sc = (col0 < 256) ? SQSL : 1.f;
                short4v o;
                o[0] = f2b(fmaf(bb.x, sc, v[0])); o[1] = f2b(fmaf(bb.y, sc, v[1]));
                o[2] = f2b(fmaf(bb.z, sc, v[2])); o[3] = f2b(fmaf(bb.w, sc, v[3]));
                *(short4v*)(Cb + (size_t)tok * 512 + wcol) = o;
            } else if (MODE == 2) {
                short4v o;
                o[0] = f2b(v[0] + bb.x); o[1] = f2b(v[1] + bb.y);
                o[2] = f2b(v[2] + bb.z); o[3] = f2b(v[3] + bb.w);
                *(short4v*)(Cb + (size_t)tok * 512 + wcol) = o;
            } else {
                const float* xr = (tok < ROWS ? x0 + (size_t)tok * 256
                                              : x1 + (size_t)(tok - ROWS) * 256);
                float4 rv = *(const float4*)(xr + wcol);
                float4 o;
                o.x = v[0] + bb.x + rv.x; o.y = v[1] + bb.y + rv.y;
                o.z = v[2] + bb.z + rv.z; o.w = v[3] + bb.w + rv.w;
                *(float4*)(Cf + (size_t)tok * 256 + wcol) = o;
            }
        }
    }
}

// ---------------------------------------------------------------------------
// Build global V^T: vtbuf[((g*4+h)*64 + d)][tok%2048].
// ---------------------------------------------------------------------------
__global__ __launch_bounds__(256)
void vtrans(const short* __restrict__ proj, short* __restrict__ vtbuf)
{
    const int tt = blockIdx.x;
    const int gh = blockIdx.y;
    const int g = gh >> 2, h = gh & 3;
    const int tid = threadIdx.x;
    const int tok0 = g * 2048 + tt * 64;

    __shared__ short Ls[64 * 76];

    {
        int c4 = tid & 15, r0 = tid >> 4;
        #pragma unroll
        for (int gg = 0; gg < 4; ++gg) {
            int r = r0 + gg * 16;
            *(short4v*)&Ls[r * 76 + c4 * 4] =
                *(const short4v*)(proj + (size_t)(tok0 + r) * 512 + 256 + h * 64 + c4 * 4);
        }
    }
    __syncthreads();

    #pragma unroll
    for (int p = 0; p < 2; ++p) {
        int ch = tid + p * 256;
        int d = ch >> 3, cc = ch & 7;
        short8 s;
        #pragma unroll
        for (int j = 0; j < 8; ++j) s[j] = Ls[(cc * 8 + j) * 76 + d];
        *(short8*)(vtbuf + (size_t)((g * 4 + h) * 64 + d) * 2048 + tt * 64 + cc * 8) = s;
    }
}

// ---------------------------------------------------------------------------
// MFMA flash cross-attention v5 — S^T, static-offset softmax (no online max:
// wq pre-scaled by sqrt(SCALE*log2e), p = exp2(St - 24); scale cancels in
// O/l). P bf16 via truncation-pack. KS/VT global loads register-prefetched.
// ---------------------------------------------------------------------------
__global__ __launch_bounds__(256)
void attn5(const short* __restrict__ proj, const short* __restrict__ vtbuf,
           short* __restrict__ mbuf)
{
    const int qt  = blockIdx.x;            // 0..31
    const int b   = blockIdx.y >> 2, h = blockIdx.y & 3;
    const int dir = blockIdx.z;
    const int tid = threadIdx.x;
    const int lane = tid & 63, wave = tid >> 6;
    const int ln   = lane & 15, quad = lane >> 4;

    const int qbase = dir * ROWS + b * 2048;
    const int kbase = (1 - dir) * ROWS + b * 2048;
    const int vg    = ((1 - dir) * 4 + b) * 4 + h;

    __shared__ short QP[64 * 72];   // Q tile then P tile (per-wave rows)
    __shared__ short KS[64 * 72];
    __shared__ short VT[64 * 72];

    const int c = tid & 7, r0 = tid >> 3;
    #pragma unroll
    for (int g = 0; g < 2; ++g) {
        int r = r0 + g * 32;
        *(short8*)&QP[r * 72 + c * 8] =
            *(const short8*)(proj + (size_t)(qbase + qt * 64 + r) * 512 + h * 64 + c * 8);
        *(short8*)&KS[r * 72 + c * 8] =
            *(const short8*)(proj + (size_t)(kbase + r) * 512 + h * 64 + c * 8);
        *(short8*)&VT[r * 72 + c * 8] =
            *(const short8*)(vtbuf + (size_t)(vg * 64 + r) * 2048 + c * 8);
    }
    __syncthreads();

    const int qrow = wave * 16 + ln;
    short8 qf0 = *(const short8*)&QP[qrow * 72 + quad * 8];
    short8 qf1 = *(const short8*)&QP[qrow * 72 + 32 + quad * 8];

    f32x4 Ot[4];
    #pragma unroll
    for (int dt = 0; dt < 4; ++dt) Ot[dt] = {0.f, 0.f, 0.f, 0.f};
    float lrun = 0.f;

    for (int j0 = 0; j0 < 2048; j0 += 64) {
        // prefetch next tile into regs (in flight during compute)
        short8 kreg[2], vreg[2];
        const bool more = (j0 + 64) < 2048;
        if (more) {
            #pragma unroll
            for (int g = 0; g < 2; ++g) {
                int r = r0 + g * 32;
                kreg[g] = *(const short8*)(proj + (size_t)(kbase + j0 + 64 + r) * 512
                                           + h * 64 + c * 8);
                vreg[g] = *(const short8*)(vtbuf + (size_t)(vg * 64 + r) * 2048
                                           + j0 + 64 + c * 8);
            }
        }

        // S^T = K @ Q^T (already in exp2 domain via wq scale)
        f32x4 St[4];
        #pragma unroll
        for (int t = 0; t < 4; ++t) {
            short8 k0 = *(const short8*)&KS[(t * 16 + ln) * 72 + quad * 8];
            short8 k1 = *(const short8*)&KS[(t * 16 + ln) * 72 + 32 + quad * 8];
            f32x4 z = {0.f, 0.f, 0.f, 0.f};
            z = __builtin_amdgcn_mfma_f32_16x16x32_bf16(k0, qf0, z, 0, 0, 0);
            St[t] = __builtin_amdgcn_mfma_f32_16x16x32_bf16(k1, qf1, z, 0, 0, 0);
        }

        // p = exp2(St - COFF); pack to bf16 by truncation; accumulate sum
        float ss = 0.f;
        #pragma unroll
        for (int t = 0; t < 4; ++t) {
            float p0 = exp2f(St[t][0] - COFF);
            float p1 = exp2f(St[t][1] - COFF);
            float p2 = exp2f(St[t][2] - COFF);
            float p3 = exp2f(St[t][3] - COFF);
            ss += (p0 + p1) + (p2 + p3);
            unsigned d0 = (__float_as_uint(p0) >> 16) |
                          (__float_as_uint(p1) & 0xffff0000u);
            unsigned d1 = (__float_as_uint(p2) >> 16) |
                          (__float_as_uint(p3) & 0xffff0000u);
            int2 pk = make_int2((int)d0, (int)d1);
            *(int2*)&QP[qrow * 72 + t * 16 + quad * 4] = pk;
        }
        ss += __shfl_xor(ss, 16);
        ss += __shfl_xor(ss, 32);
        lrun += ss;

        // O^T += V^T @ P^T
        short8 p0 = *(const short8*)&QP[qrow * 72 + quad * 8];
        short8 p1 = *(const short8*)&QP[qrow * 72 + 32 + quad * 8];
        #pragma unroll
        for (int dt = 0; dt < 4; ++dt) {
            short8 v0 = *(const short8*)&VT[(dt * 16 + ln) * 72 + quad * 8];
            short8 v1 = *(const short8*)&VT[(dt * 16 + ln) * 72 + 32 + quad * 8];
            Ot[dt] = __builtin_amdgcn_mfma_f32_16x16x32_bf16(v0, p0, Ot[dt], 0, 0, 0);
            Ot[dt] = __builtin_amdgcn_mfma_f32_16x16x32_bf16(v1, p1, Ot[dt], 0, 0, 0);
        }
        __syncthreads();   // KS/VT reads done

        if (more) {
            #pragma unroll
            for (int g = 0; g < 2; ++g) {
                int r = r0 + g * 32;
                *(short8*)&KS[r * 72 + c * 8] = kreg[g];
                *(short8*)&VT[r * 72 + c * 8] = vreg[g];
            }
        }
        __syncthreads();   // staging visible
    }

    float li = 1.f / lrun;
    int tok = qbase + qt * 64 + qrow;
    #pragma unroll
    for (int dt = 0; dt < 4; ++dt) {
        short4v o;
        #pragma unroll
        for (int r = 0; r < 4; ++r) o[r] = f2b(Ot[dt][r] * li);
        *(short4v*)(mbuf + (size_t)tok * 256 + h * 64 + dt * 16 + quad * 4) = o;
    }
}

// ---------------------------------------------------------------------------
// In-place LayerNorm(512) + exact GELU on bf16 rows. One wave per row.
// ---------------------------------------------------------------------------
__global__ __launch_bounds__(256)
void ln_gelu2(short* __restrict__ h, const float* __restrict__ gamma,
              const float* __restrict__ beta)
{
    const int wave = threadIdx.x >> 6, lane = threadIdx.x & 63;
    const int row = blockIdx.x * 4 + wave;
    short* hp = h + (size_t)row * 512 + lane * 8;
    short8 sv = *(const short8*)hp;
    float v[8], s1 = 0.f, s2 = 0.f;
    #pragma unroll
    for (int i = 0; i < 8; ++i) { v[i] = b2f(sv[i]); s1 += v[i]; s2 += v[i] * v[i]; }
    #pragma unroll
    for (int off = 32; off; off >>= 1) {
        s1 += __shfl_xor(s1, off);
        s2 += __shfl_xor(s2, off);
    }
    float mean = s1 * (1.f / 512.f);
    float var  = s2 * (1.f / 512.f) - mean * mean;
    float rstd = rsqrtf(var + 1e-5f);
    #pragma unroll
    for (int i = 0; i < 8; ++i) {
        int o = lane * 8 + i;
        float y = (v[i] - mean) * rstd * gamma[o] + beta[o];
        sv[i] = f2b(0.5f * y * (1.f + erff(y * 0.70710678118654752f)));
    }
    *(short8*)hp = sv;
}

// ---------------------------------------------------------------------------
extern "C" void kernel_launch(void* const* d_in, const int* in_sizes, int n_in,
                              void* d_out, int out_size, void* d_ws, size_t ws_size,
                              hipStream_t stream)
{
    const float* x0    = (const float*)d_in[0];
    const float* x1    = (const float*)d_in[1];
    const float* Wqk   = (const float*)d_in[2];
    const float* bqk   = (const float*)d_in[3];
    const float* Wv    = (const float*)d_in[4];
    const float* bv    = (const float*)d_in[5];
    const float* Wp    = (const float*)d_in[6];
    const float* bp    = (const float*)d_in[7];
    const float* W1    = (const float*)d_in[8];
    const float* b1    = (const float*)d_in[9];
    const float* gamma = (const float*)d_in[10];
    const float* beta  = (const float*)d_in[11];
    const float* W2    = (const float*)d_in[12];
    const float* b2    = (const float*)d_in[13];
    float* out = (float*)d_out;

    char* ws = (char*)d_ws;
    const size_t MB = 1024 * 1024;
    short* xbf  = (short*)ws;                    // [16384,256]  8 MB
    short* proj = (short*)(ws + 8  * MB);        // [16384,512] 16 MB (-> hbuf)
    short* vtb  = (short*)(ws + 24 * MB);        // [2048,2048]  8 MB
    short* mbuf = (short*)(ws + 32 * MB);        // [16384,256]  8 MB
    short* wq   = (short*)(ws + 40 * MB);
    short* wv   = wq + 65536;
    short* wp   = wv + 65536;
    short* w1   = wp + 65536;
    short* w2   = w1 + 262144;
    short* wc   = w2 + 131072;                   // [512,256] fused W1b@Wp
    float* bc   = (float*)(wc + 131072);         // [512] fused bias
    short* hbuf = proj;                          // overlays proj (dead after attn)

    cvt_all<<<dim3(2048, 7), 256, 0, stream>>>(x0, x1, Wqk, Wv, Wp, W1, W2,
                                               xbf, wq, wv, wp, w1, w2);
    wcomp<<<512, 256, 0, stream>>>(w1, wp, wc);
    bcomp<<<2, 256, 0, stream>>>(w1, bp, b1, bc);
    gemm5<0><<<dim3(4, 256), 256, 0, stream>>>(xbf, nullptr, wq, wv, bqk, bv,
                                               nullptr, nullptr, proj, nullptr);
    vtrans<<<dim3(32, 32), 256, 0, stream>>>(proj, vtb);
    attn5<<<dim3(32, 16, 2), 256, 0, stream>>>(proj, vtb, mbuf);
    gemm5<2><<<dim3(4, 256), 256, 0, stream>>>(xbf, mbuf, w1, wc, bc, nullptr,
                                               nullptr, nullptr, hbuf, nullptr);
    ln_gelu2<<<4096, 256, 0, stream>>>(hbuf, gamma, beta);
    gemm5<3><<<dim3(2, 256), 256, 0, stream>>>(hbuf, nullptr, w2, nullptr, b2, nullptr,
                                               x0, x1, nullptr, out);
}